// Round 4
// baseline (253.786 us; speedup 1.0000x reference)
//
#include <hip/hip_runtime.h>

// FM_FTRL == two unit-lower-triangular solves (R1/R2 analysis):
//   alpha_i = -2eta*(x_0.x_i - q0*q_i)  (closed form, K_A=1; alpha_0 = 1)
//   (I+Lh)s = r, Lh[i,j] = 2eta*(x_j.x_i) j<i
//   r_i = 2*(alpha_i^2*T0 - b_i) (i>=1), r_0 = 2*(s0 + T0 - b_0)
//   preds = s/2 + b ;  K_B=2: s ~= r - L r + L^2 r
// R3 postmortem: barrier-drain theory WRONG (reg-staging changed nothing).
// VALUBusy 18.7% x 54.7us == act-wave VALU time: only 260/1024 threads
// computed (2 act waves/SIMD, 80% stalled on LDS latency). R4: spread FLOPs
// over 16 e-bands (880 gram threads, 8 waves/SIMD working); same for k_term
// (640 sweep threads, LDS-staged chunk instead of 40-lane strided global).

#define NN 20000
#define CC 40
#define NCH 500
#define ETA2 2e-5f

// ws float offsets (total ~9.9 MB)
#define OFF_GRAM 0L          // 500 chunks x 780 packed lower-tri
#define OFF_ZR   390016L
#define OFF_Z1   902016L
#define OFF_S1   1414016L
#define OFF_S2   1926016L
#define OFF_SCLP 2438016L    // [0..31] T0 partials, [32] s0
#define OFF_ACC  2438056L
#define OFF_TV   2458056L
#define OFF_X0   2478080L    // x0 column, contiguous (1024)

// ---------------- k0: T0/s0 partials + x0 stash + b-copy -------------------
__global__ __launch_bounds__(1024) void k_init(
    const float* __restrict__ At, const float* __restrict__ bvec,
    const float* __restrict__ w1, const float* __restrict__ W2,
    float* __restrict__ out, float* __restrict__ scalp,
    float* __restrict__ x0ws) {
  __shared__ float x0s[1024];
  __shared__ float part[16];
  const int bid = blockIdx.x, t = threadIdx.x;
  const int wid = t >> 6, lane = t & 63;

  if (bid < 32) {  // T0 partial over 16 W2 rows
    x0s[t] = (t < 1023) ? At[(long)t * NN] : 0.f;
    __syncthreads();
    const int row = bid * 16 + wid;
    float p = 0.f;
#pragma unroll
    for (int k = 0; k < 16; ++k) {
      const int ci = k * 64 + lane;
      if (ci < 1023) p = fmaf(W2[(long)row * 1023 + ci], x0s[ci], p);
    }
#pragma unroll
    for (int o = 32; o > 0; o >>= 1) p += __shfl_down(p, o);
    if (lane == 0) part[wid] = p * p;
    __syncthreads();
    if (t == 0) {
      float s = 0.f;
#pragma unroll
      for (int k = 0; k < 16; ++k) s += part[k];
      scalp[bid] = s;
    }
  } else if (bid == 32) {  // s0 = w1 . x0 ; also stash x0 contiguously
    const float xv = At[(long)t * NN];
    x0ws[t] = xv;
    float p = w1[t] * xv;
#pragma unroll
    for (int o = 32; o > 0; o >>= 1) p += __shfl_down(p, o);
    if (lane == 0) part[wid] = p;
    __syncthreads();
    if (t == 0) {
      float s = 0.f;
#pragma unroll
      for (int k = 0; k < 16; ++k) s += part[k];
      scalp[32] = s;
    }
  } else {  // b-copy: 20 blocks x 1000
    const int i = (bid - 33) * 1000 + t;
    if (t < 1000) out[NN + i] = bvec[i];
  }
}

// ---------------- k1: packed chunk Grams + alpha + r + Zr ------------------
// 880 gram threads: 55 lower-tri 4x4 tiles x 16 e-bands (8 rows/stage each).
// 40 u threads (4 bands x 10 float4-cols). Reg-staged dbuf, one barrier/stage.
// Post-loop: rs from q-row (xt[1] row 127) BEFORE xt is reused as reduction
// scratch. Partials laid out scr[band*880 + t] -> reduce reads are
// lane-consecutive (conflict-free).
struct GramSh {
  __align__(16) float xt[2][5120];  // 40,960 B dbuf; reused as bands 0..10
  __align__(16) float scrB[4400];   // bands 11..15
  float x0s[1024];
  float up[160];
  __align__(16) float rs[CC];
  float sc[2];
};
static_assert(sizeof(GramSh) <= 64 * 1024, "LDS overflow");

__global__ __launch_bounds__(1024, 8) void k_gram(
    const float* __restrict__ At, const float* __restrict__ bvec,
    const float* __restrict__ x0g, float* __restrict__ gram,
    float* __restrict__ Zr, const float* __restrict__ scalp,
    float* __restrict__ acc) {
  __shared__ GramSh sh;
  const int c = blockIdx.x, t = threadIdx.x;
  const long i0 = (long)c * CC;

  sh.x0s[t] = x0g[t];  // contiguous, L3-hot (written once by k_init)
  if (t == 0) {
    float T = 0.f;
#pragma unroll
    for (int k = 0; k < 32; ++k) T += scalp[k];
    sh.sc[0] = T;
    sh.sc[1] = scalp[32];
  }

  // staging addresses: idx=t and idx=1024+t; LDS float offset = 4*idx
  const float* g1 = At + (long)(t / 10) * NN + i0 + 4 * (t % 10);
  const float* g2 =
      At + (long)((1024 + t) / 10) * NN + i0 + 4 * ((1024 + t) % 10);

  // roles
  const bool act = (t < 880);
  int a = 0, bb = 0, band = 0, tile = 0;
  if (act) {
    tile = t % 55; band = t / 55;
    int r = tile; while (r > a) { r -= ++a; } bb = r;
  }
  const bool uact = (t >= 880 && t < 920);
  const int uz = t - 880;                       // 0..39
  const int uband = uz / 10, uq = uz - uband * 10;
  float4 uac4 = make_float4(0.f, 0.f, 0.f, 0.f);

  float ac[4][4];
#pragma unroll
  for (int r = 0; r < 4; ++r)
#pragma unroll
    for (int s = 0; s < 4; ++s) ac[r][s] = 0.f;

  // prologue: stage 0 into registers
  float4 r1 = *(const float4*)g1;
  float4 r2 = make_float4(0.f, 0.f, 0.f, 0.f);
  if (t < 256) r2 = *(const float4*)g2;

  const int e0g = band * 8;
  const int e0u = uband * 32;

  // One barrier/stage is safe: a wave at write(st+1) implies all waves
  // passed barrier(st); laggards are in compute(st) on the OTHER buffer.
  for (int st = 0; st < 8; ++st) {
    float* nb = sh.xt[st & 1];
    *(float4*)&nb[4 * t] = r1;
    if (t < 256) *(float4*)&nb[4096 + 4 * t] = r2;
    if (st < 7) {  // issue next stage loads; they fly across the barrier
      const long adv = (long)(st + 1) * (128L * NN);
      r1 = *(const float4*)(g1 + adv);
      if (t < 256) r2 = *(const float4*)(g2 + adv);
    }
    asm volatile("s_waitcnt lgkmcnt(0)\n\ts_barrier" ::: "memory");
    const float* __restrict__ xs = sh.xt[st & 1];
    if (act) {
#pragma unroll
      for (int k = 0; k < 8; ++k) {
        const float* row = xs + (e0g + k) * 40;
        const float4 ra = *(const float4*)(row + 4 * a);
        const float4 rb = *(const float4*)(row + 4 * bb);
        ac[0][0] = fmaf(ra.x, rb.x, ac[0][0]); ac[0][1] = fmaf(ra.x, rb.y, ac[0][1]);
        ac[0][2] = fmaf(ra.x, rb.z, ac[0][2]); ac[0][3] = fmaf(ra.x, rb.w, ac[0][3]);
        ac[1][0] = fmaf(ra.y, rb.x, ac[1][0]); ac[1][1] = fmaf(ra.y, rb.y, ac[1][1]);
        ac[1][2] = fmaf(ra.y, rb.z, ac[1][2]); ac[1][3] = fmaf(ra.y, rb.w, ac[1][3]);
        ac[2][0] = fmaf(ra.z, rb.x, ac[2][0]); ac[2][1] = fmaf(ra.z, rb.y, ac[2][1]);
        ac[2][2] = fmaf(ra.z, rb.z, ac[2][2]); ac[2][3] = fmaf(ra.z, rb.w, ac[2][3]);
        ac[3][0] = fmaf(ra.w, rb.x, ac[3][0]); ac[3][1] = fmaf(ra.w, rb.y, ac[3][1]);
        ac[3][2] = fmaf(ra.w, rb.z, ac[3][2]); ac[3][3] = fmaf(ra.w, rb.w, ac[3][3]);
      }
    } else if (uact) {
#pragma unroll 4
      for (int le = e0u; le < e0u + 32; ++le) {
        const float4 v = *(const float4*)(xs + le * 40 + 4 * uq);
        const float xv = sh.x0s[st * 128 + le];
        uac4.x = fmaf(xv, v.x, uac4.x);
        uac4.y = fmaf(xv, v.y, uac4.y);
        uac4.z = fmaf(xv, v.z, uac4.z);
        uac4.w = fmaf(xv, v.w, uac4.w);
      }
    }
  }
  if (uact) *(float4*)&sh.up[uband * 40 + 4 * uq] = uac4;
  __syncthreads();  // B1: up published; stage-7 compute done everywhere

  // alpha (closed form) -> r ; q row = stage-7 local row 127 (buf 1), intact
  if (t < CC) {
    const long gi = i0 + t;
    const float uu = sh.up[t] + sh.up[40 + t] + sh.up[80 + t] + sh.up[120 + t];
    const float qi = sh.xt[1][127 * 40 + t];
    const float q0 = sh.x0s[1023];
    const float al = (gi == 0) ? 1.f : -ETA2 * (uu - q0 * qi);
    const float T0 = sh.sc[0], s0v = sh.sc[1];
    const float bv = bvec[gi];
    float r = 2.f * fmaf(al * al, T0, -bv);
    if (gi == 0) r = 2.f * (s0v + T0 - bv);
    sh.rs[t] = r;
    acc[gi] = r;
  }
  __syncthreads();  // B2: rs published; q-row consumed -> xt reusable

  float* xtf = &sh.xt[0][0];
  if (act) {  // all 16 bands stash partials: scr[band*880 + tile*16 + e]
    float* dst = (band <= 10) ? &xtf[band * 880 + tile * 16]
                              : &sh.scrB[(band - 11) * 880 + tile * 16];
#pragma unroll
    for (int r = 0; r < 4; ++r)
#pragma unroll
      for (int s = 0; s < 4; ++s) dst[r * 4 + s] = ac[r][s];
  }
  __syncthreads();  // B3: partials published

  // Zr[c][e] = sum_j r_j X[e][i0+j]  (chunk rows are L2-hot)
  {
    const float* xr = At + (long)t * NN + i0;
    float z = 0.f;
#pragma unroll
    for (int j4 = 0; j4 < 10; ++j4) {
      const float4 x = *(const float4*)(xr + 4 * j4);
      const float4 rq = *(const float4*)&sh.rs[4 * j4];
      z = fmaf(x.x, rq.x, z); z = fmaf(x.y, rq.y, z);
      z = fmaf(x.z, rq.z, z); z = fmaf(x.w, rq.w, z);
    }
    Zr[(long)c * 1024 + t] = z;
  }

  // reduce 16 bands (lane-consecutive reads, conflict-free) + packed store
  if (t < 880) {
    const int tile2 = t >> 4, e2 = t & 15;
    int a2 = 0, r2d = tile2;
    while (r2d > a2) { r2d -= ++a2; }
    const int bb2 = r2d;
    float v = 0.f;
#pragma unroll
    for (int k = 0; k <= 10; ++k) v += xtf[k * 880 + t];
#pragma unroll
    for (int k = 0; k < 5; ++k) v += sh.scrB[k * 880 + t];
    const int row = 4 * a2 + (e2 >> 2);
    const int col = 4 * bb2 + (e2 & 3);
    if (col < row) gram[(long)c * 780 + row * (row - 1) / 2 + col] = v;
  }
}

// ---------------- scan: S[c][e] = sum_{cp<c} Z[cp][e] ----------------------
__global__ __launch_bounds__(1024) void k_scan(const float* __restrict__ Z,
                                               float* __restrict__ S) {
  __shared__ float gsum[32][32];
  const int t = threadIdx.x;
  const int ei = t & 31, ci = t >> 5;
  const int e = blockIdx.x * 32 + ei;
  const int c0 = ci * 16;
  const int c1 = (c0 + 16 < NCH) ? c0 + 16 : NCH;

  float s = 0.f;
  for (int base = c0; base < c1; base += 8) {
    float v[8];
#pragma unroll
    for (int k = 0; k < 8; ++k) {
      const int cc = base + k;
      v[k] = (cc < c1) ? Z[(long)cc * 1024 + e] : 0.f;
    }
#pragma unroll
    for (int k = 0; k < 8; ++k) s += v[k];
  }
  gsum[ci][ei] = s;
  __syncthreads();

  float off = 0.f;
#pragma unroll
  for (int k = 0; k < 31; ++k)
    if (k < ci) off += gsum[k][ei];

  s = off;
  for (int base = c0; base < c1; base += 8) {
    float v[8];
#pragma unroll
    for (int k = 0; k < 8; ++k) {
      const int cc = base + k;
      v[k] = (cc < c1) ? Z[(long)cc * 1024 + e] : 0.f;
    }
#pragma unroll
    for (int k = 0; k < 8; ++k) {
      const int cc = base + k;
      if (cc < c1) S[(long)cc * 1024 + e] = s;
      s += v[k];
    }
  }
}

// ---------------- term: w = -(L v)  --------------------------------------
// LDS-staged sweep: 640 threads (40 i x 16 e-bands) read the reg-staged
// chunk from LDS (was: 40/64 lanes x 64 strided global granule loads).
// LAST=false: v = r (acc), w = t1 ; tvec=t1, acc=r+t1, Z1.
// LAST=true : v = t1 (tvec), w = t2 ; out = 0.5*(acc+t2) + b.
struct TermSh {
  __align__(16) float xt[2][5120];  // 40,960 B dbuf
  float Sm[1024];
  float red[640];
  __align__(16) float vvs[CC], wvs[CC];
};
static_assert(sizeof(TermSh) <= 64 * 1024, "LDS overflow");

template <bool LAST>
__global__ __launch_bounds__(1024, 8) void k_term(
    const float* __restrict__ At, const float* __restrict__ bvec,
    const float* __restrict__ gram, const float* __restrict__ S,
    float* __restrict__ Z1, float* __restrict__ acc, float* __restrict__ tvec,
    float* __restrict__ out) {
  __shared__ TermSh sh;
  const int c = blockIdx.x, t = threadIdx.x;
  const long i0 = (long)c * CC;

  sh.Sm[t] = S[(long)c * 1024 + t];
  if (t < CC) sh.vvs[t] = LAST ? tvec[i0 + t] : acc[i0 + t];

  const float* g1 = At + (long)(t / 10) * NN + i0 + 4 * (t % 10);
  const float* g2 =
      At + (long)((1024 + t) / 10) * NN + i0 + 4 * ((1024 + t) % 10);

  const bool sact = (t < 640);
  const int si = t % 40, sband = t / 40;  // 16 bands x 8 rows/stage
  float p = 0.f;

  float4 r1 = *(const float4*)g1;
  float4 r2 = make_float4(0.f, 0.f, 0.f, 0.f);
  if (t < 256) r2 = *(const float4*)g2;

  for (int st = 0; st < 8; ++st) {
    float* nb = sh.xt[st & 1];
    *(float4*)&nb[4 * t] = r1;
    if (t < 256) *(float4*)&nb[4096 + 4 * t] = r2;
    if (st < 7) {
      const long adv = (long)(st + 1) * (128L * NN);
      r1 = *(const float4*)(g1 + adv);
      if (t < 256) r2 = *(const float4*)(g2 + adv);
    }
    asm volatile("s_waitcnt lgkmcnt(0)\n\ts_barrier" ::: "memory");
    if (sact) {
      const float* __restrict__ xs = sh.xt[st & 1];
      const float* __restrict__ sv = &sh.Sm[st * 128];
#pragma unroll
      for (int k = 0; k < 8; ++k) {
        const int le = sband * 8 + k;
        p = fmaf(xs[le * 40 + si], sv[le], p);
      }
    }
  }
  if (sact) sh.red[t] = p;
  __syncthreads();

  if (t < CC) {
    const int i = t;
    float dot = 0.f;
#pragma unroll
    for (int k = 0; k < 16; ++k) dot += sh.red[k * 40 + i];
    const float* grow = gram + (long)c * 780 + i * (i - 1) / 2;
    float g = 0.f;
#pragma unroll 8
    for (int j = 0; j < i; ++j) g = fmaf(grow[j], sh.vvs[j], g);
    const float w = -ETA2 * (dot + g);
    if (LAST) {
      out[i0 + i] = fmaf(0.5f, acc[i0 + i] + w, bvec[i0 + i]);
    } else {
      sh.wvs[i] = w;
      tvec[i0 + i] = w;
      acc[i0 + i] += w;
    }
  }
  if (!LAST) {
    __syncthreads();
    const float* xr = At + (long)t * NN + i0;
    float z = 0.f;
#pragma unroll
    for (int j4 = 0; j4 < 10; ++j4) {
      const float4 x = *(const float4*)(xr + 4 * j4);
      const float4 wq = *(const float4*)&sh.wvs[4 * j4];
      z = fmaf(x.x, wq.x, z); z = fmaf(x.y, wq.y, z);
      z = fmaf(x.z, wq.z, z); z = fmaf(x.w, wq.w, z);
    }
    Z1[(long)c * 1024 + t] = z;
  }
}

extern "C" void kernel_launch(void* const* d_in, const int* in_sizes, int n_in,
                              void* d_out, int out_size, void* d_ws,
                              size_t ws_size, hipStream_t stream) {
  const float* At = (const float*)d_in[0];  // (1024, 20000) row-major
  const float* b  = (const float*)d_in[1];
  const float* w1 = (const float*)d_in[2];
  const float* W2 = (const float*)d_in[3];  // (512, 1023) row-major
  float* out = (float*)d_out;
  float* ws = (float*)d_ws;

  float* gram  = ws + OFF_GRAM;
  float* Zr    = ws + OFF_ZR;
  float* Z1    = ws + OFF_Z1;
  float* S1    = ws + OFF_S1;
  float* S2    = ws + OFF_S2;
  float* scalp = ws + OFF_SCLP;
  float* acc   = ws + OFF_ACC;
  float* tvec  = ws + OFF_TV;
  float* x0ws  = ws + OFF_X0;

  k_init<<<dim3(53), dim3(1024), 0, stream>>>(At, b, w1, W2, out, scalp, x0ws);
  k_gram<<<dim3(NCH), dim3(1024), 0, stream>>>(At, b, x0ws, gram, Zr, scalp,
                                               acc);
  k_scan<<<dim3(32), dim3(1024), 0, stream>>>(Zr, S1);
  k_term<false><<<dim3(NCH), dim3(1024), 0, stream>>>(At, b, gram, S1, Z1, acc,
                                                      tvec, out);
  k_scan<<<dim3(32), dim3(1024), 0, stream>>>(Z1, S2);
  k_term<true><<<dim3(NCH), dim3(1024), 0, stream>>>(At, b, gram, S2, Z1, acc,
                                                     tvec, out);
}

// Round 5
// 241.650 us; speedup vs baseline: 1.0502x; 1.0502x over previous
//
#include <hip/hip_runtime.h>

// FM_FTRL == two unit-lower-triangular solves:
//   alpha_i = -2eta*(x_0.x_i - q0*q_i)  (closed form, K_A=1; alpha_0 = 1)
//   (I+Lh)s = r, Lh[i,j] = 2eta*(x_j.x_i) j<i
//   r_i = 2*(alpha_i^2*T0 - b_i) (i>=1), r_0 = 2*(s0 + T0 - b_0)
//   preds = s/2 + b ;  K_B=2: s ~= r - L r + L^2 r
// R4 postmortem: WRITE_SIZE 98MB == register spill (VGPR capped 32 by
// launch_bounds(1024,8)); and across R2-R4 dur == traffic/2.7TB/s ->
// the kernels are L2-miss-BYTE-bound. R5: CC=20, chunk (82KB) RETAINED in
// LDS [j][e]-transposed -> Zr/Z1 re-read misses (~100MB) eliminated;
// launch_bounds(1024,4) kills spill; scans in-place; half-split staging.

#define NN 20000
#define CC 20
#define NCH 1000
#define ETA2 2e-5f
#define XPAD 1028  // xl row stride (floats): 16B-aligned, banks spread

// ws float offsets (~9.1 MB)
#define OFF_GRAM 0L        // 1000 chunks x 190 packed lower-tri
#define OFF_ZR   190016L   // 1000 x 1024; scanned IN PLACE -> S1
#define OFF_Z1   1214016L  // 1000 x 1024; scanned IN PLACE -> S2
#define OFF_SCLP 2238016L  // [0..31] T0 partials, [32] s0
#define OFF_ACC  2238080L
#define OFF_TV   2258080L
#define OFF_X0   2278144L  // x0 column, contiguous (1024)

// ---------------- k0: T0/s0 partials + x0 stash + b-copy -------------------
__global__ __launch_bounds__(1024) void k_init(
    const float* __restrict__ At, const float* __restrict__ bvec,
    const float* __restrict__ w1, const float* __restrict__ W2,
    float* __restrict__ out, float* __restrict__ scalp,
    float* __restrict__ x0ws) {
  __shared__ float x0s[1024];
  __shared__ float part[16];
  const int bid = blockIdx.x, t = threadIdx.x;
  const int wid = t >> 6, lane = t & 63;

  if (bid < 32) {  // T0 partial over 16 W2 rows
    x0s[t] = (t < 1023) ? At[(long)t * NN] : 0.f;
    __syncthreads();
    const int row = bid * 16 + wid;
    float p = 0.f;
#pragma unroll
    for (int k = 0; k < 16; ++k) {
      const int ci = k * 64 + lane;
      if (ci < 1023) p = fmaf(W2[(long)row * 1023 + ci], x0s[ci], p);
    }
#pragma unroll
    for (int o = 32; o > 0; o >>= 1) p += __shfl_down(p, o);
    if (lane == 0) part[wid] = p * p;
    __syncthreads();
    if (t == 0) {
      float s = 0.f;
#pragma unroll
      for (int k = 0; k < 16; ++k) s += part[k];
      scalp[bid] = s;
    }
  } else if (bid == 32) {  // s0 = w1 . x0 ; stash x0 contiguously
    const float xv = At[(long)t * NN];
    x0ws[t] = xv;
    float p = w1[t] * xv;
#pragma unroll
    for (int o = 32; o > 0; o >>= 1) p += __shfl_down(p, o);
    if (lane == 0) part[wid] = p;
    __syncthreads();
    if (t == 0) {
      float s = 0.f;
#pragma unroll
      for (int k = 0; k < 16; ++k) s += part[k];
      scalp[32] = s;
    }
  } else {  // b-copy: 20 blocks x 1000
    const int i = (bid - 33) * 1000 + t;
    if (t < 1000) out[NN + i] = bvec[i];
  }
}

// Staged-chunk layout: xl[j*XPAD + e] = At[e][i0+j], j<20, e<1024.
// f4 index g in [0,5120): e=g/5, q=g%5 -> src At[e][i0+4q..+3] (coalesced-ish
// 80B row segments); transposed ds_writes spread banks via XPAD=1028.
#define STAGE_LD(g, dst)                                            \
  {                                                                 \
    const int e_ = (g) / 5, q_ = (g) - 5 * e_;                      \
    dst = *(const float4*)(At + (long)e_ * NN + i0 + 4 * q_);       \
  }
#define STAGE_ST(g, src, xl)                                        \
  {                                                                 \
    const int e_ = (g) / 5, q_ = (g) - 5 * e_;                      \
    xl[(4 * q_ + 0) * XPAD + e_] = src.x;                           \
    xl[(4 * q_ + 1) * XPAD + e_] = src.y;                           \
    xl[(4 * q_ + 2) * XPAD + e_] = src.z;                           \
    xl[(4 * q_ + 3) * XPAD + e_] = src.w;                           \
  }

// ---------------- k1: packed chunk Grams + alpha + r + Zr ------------------
// 480 gram threads: 15 lower-tri 4x4 tiles x 32 e-slices (strided f4:
// f = band + 32k, conflict-free). 80 u threads. Zr read from RETAINED LDS.
struct GramSh {
  __align__(16) float xl[CC * XPAD];  // 82,240 B
  __align__(16) float x0s[1024];
  __align__(16) float scr[32 * 241];  // band partials, padded rows
  float up[80];
  float rs[CC];
  float sc[2];
};

__global__ __launch_bounds__(1024, 4) void k_gram(
    const float* __restrict__ At, const float* __restrict__ bvec,
    const float* __restrict__ x0g, float* __restrict__ gram,
    float* __restrict__ Zr, const float* __restrict__ scalp,
    float* __restrict__ acc) {
  __shared__ GramSh sh;
  const int c = blockIdx.x, t = threadIdx.x;
  const long i0 = (long)c * CC;

  sh.x0s[t] = x0g[t];
  if (t == 0) {
    float T = 0.f;
#pragma unroll
    for (int k = 0; k < 32; ++k) T += scalp[k];
    sh.sc[0] = T;
    sh.sc[1] = scalp[32];
  }

  // roles
  const bool act = (t < 480);
  int a = 0, bb = 0, band = 0;
  if (act) {
    const int tile = t % 15;
    band = t / 15;
    int r = tile;
    while (r > a) { r -= ++a; }
    bb = r;
  }
  const bool uact = (t >= 480 && t < 560);
  const int uz = t - 480, ui = uz % 20, ub = uz / 20;
  float4 uac = make_float4(0.f, 0.f, 0.f, 0.f);

  float ac[4][4];
#pragma unroll
  for (int r = 0; r < 4; ++r)
#pragma unroll
    for (int s = 0; s < 4; ++s) ac[r][s] = 0.f;

  // ---- stage half 0 (e<512: f4 [0,2560)) ----
  float4 ha, hb, hc;
  STAGE_LD(t, ha);
  STAGE_LD(1024 + t, hb);
  if (t < 512) STAGE_LD(2048 + t, hc);
  STAGE_ST(t, ha, sh.xl);
  STAGE_ST(1024 + t, hb, sh.xl);
  if (t < 512) STAGE_ST(2048 + t, hc, sh.xl);
  __syncthreads();

  // ---- issue half-1 loads (fly over phase-0 compute) ----
  STAGE_LD(2560 + t, ha);
  STAGE_LD(3584 + t, hb);
  if (t < 512) STAGE_LD(4608 + t, hc);

#define GRAM_PHASE(H)                                                        \
  if (act) {                                                                 \
    _Pragma("unroll") for (int k = 0; k < 4; ++k) {                          \
      const int e0 = (H) * 512 + (band + 32 * k) * 4;                        \
      const float4 ra0 = *(const float4*)&sh.xl[(4 * a + 0) * XPAD + e0];    \
      const float4 ra1 = *(const float4*)&sh.xl[(4 * a + 1) * XPAD + e0];    \
      const float4 ra2 = *(const float4*)&sh.xl[(4 * a + 2) * XPAD + e0];    \
      const float4 ra3 = *(const float4*)&sh.xl[(4 * a + 3) * XPAD + e0];    \
      const float4 rb0 = *(const float4*)&sh.xl[(4 * bb + 0) * XPAD + e0];   \
      const float4 rb1 = *(const float4*)&sh.xl[(4 * bb + 1) * XPAD + e0];   \
      const float4 rb2 = *(const float4*)&sh.xl[(4 * bb + 2) * XPAD + e0];   \
      const float4 rb3 = *(const float4*)&sh.xl[(4 * bb + 3) * XPAD + e0];   \
      const float4 RA[4] = {ra0, ra1, ra2, ra3};                             \
      const float4 RB[4] = {rb0, rb1, rb2, rb3};                             \
      _Pragma("unroll") for (int r = 0; r < 4; ++r)                          \
          _Pragma("unroll") for (int s = 0; s < 4; ++s) {                    \
        ac[r][s] = fmaf(RA[r].x, RB[s].x, ac[r][s]);                         \
        ac[r][s] = fmaf(RA[r].y, RB[s].y, ac[r][s]);                         \
        ac[r][s] = fmaf(RA[r].z, RB[s].z, ac[r][s]);                         \
        ac[r][s] = fmaf(RA[r].w, RB[s].w, ac[r][s]);                         \
      }                                                                      \
    }                                                                        \
  } else if (uact) {                                                         \
    _Pragma("unroll") for (int k = 0; k < 32; ++k) {                         \
      const int e0 = (H) * 512 + (ub + 4 * k) * 4;                           \
      const float4 xv = *(const float4*)&sh.xl[ui * XPAD + e0];              \
      const float4 x0 = *(const float4*)&sh.x0s[e0];                         \
      uac.x = fmaf(x0.x, xv.x, uac.x);                                       \
      uac.y = fmaf(x0.y, xv.y, uac.y);                                       \
      uac.z = fmaf(x0.z, xv.z, uac.z);                                       \
      uac.w = fmaf(x0.w, xv.w, uac.w);                                       \
    }                                                                        \
  }

  GRAM_PHASE(0)

  // ---- store half 1 (disjoint e>=512 vs phase-0 readers), barrier ----
  STAGE_ST(2560 + t, ha, sh.xl);
  STAGE_ST(3584 + t, hb, sh.xl);
  if (t < 512) STAGE_ST(4608 + t, hc, sh.xl);
  __syncthreads();

  GRAM_PHASE(1)

  if (act) {  // stash band partials: scr[band][tile*16 + r*4+s], pad 241
    const int tile = t % 15;
#pragma unroll
    for (int r = 0; r < 4; ++r)
#pragma unroll
      for (int s = 0; s < 4; ++s)
        sh.scr[band * 241 + tile * 16 + r * 4 + s] = ac[r][s];
  }
  if (uact) sh.up[ub * 20 + ui] = uac.x + uac.y + uac.z + uac.w;
  __syncthreads();

  // alpha (closed form) -> r
  if (t < CC) {
    const long gi = i0 + t;
    const float uu = sh.up[t] + sh.up[20 + t] + sh.up[40 + t] + sh.up[60 + t];
    const float qi = sh.xl[t * XPAD + 1023];  // X[1023][i0+t]
    const float q0 = sh.x0s[1023];
    const float al = (gi == 0) ? 1.f : -ETA2 * (uu - q0 * qi);
    const float T0 = sh.sc[0], s0v = sh.sc[1];
    const float bv = bvec[gi];
    float r = 2.f * fmaf(al * al, T0, -bv);
    if (gi == 0) r = 2.f * (s0v + T0 - bv);
    sh.rs[t] = r;
    acc[gi] = r;
  }
  __syncthreads();

  // Zr from RETAINED LDS chunk (no global re-read)
  {
    float z = 0.f;
#pragma unroll
    for (int j = 0; j < CC; ++j) z = fmaf(sh.rs[j], sh.xl[j * XPAD + t], z);
    Zr[(long)c * 1024 + t] = z;
  }

  // reduce 32 band-partials + packed store (col<row)
  if (t < 240) {
    const int tile2 = t >> 4, e2 = t & 15;
    int a2 = 0, r2 = tile2;
    while (r2 > a2) { r2 -= ++a2; }
    const int bb2 = r2;
    float v = 0.f;
#pragma unroll
    for (int k = 0; k < 32; ++k) v += sh.scr[k * 241 + t];
    const int row = 4 * a2 + (e2 >> 2);
    const int col = 4 * bb2 + (e2 & 3);
    if (col < row) gram[(long)c * 190 + row * (row - 1) / 2 + col] = v;
  }
}

// ---------------- scan: IN PLACE Z -> exclusive prefix S -------------------
// 32 blocks x (32 c-groups x 32 e-lanes); chain 32, loads 8-batched.
__global__ __launch_bounds__(1024) void k_scan(float* __restrict__ Z) {
  __shared__ float gsum[32][33];
  const int t = threadIdx.x;
  const int ei = t & 31, ci = t >> 5;
  const int e = blockIdx.x * 32 + ei;
  const int c0 = ci * 32;
  const int c1 = (c0 + 32 < NCH) ? c0 + 32 : NCH;

  float s = 0.f;
  for (int base = c0; base < c1; base += 8) {
    float v[8];
#pragma unroll
    for (int k = 0; k < 8; ++k) {
      const int cc = base + k;
      v[k] = (cc < c1) ? Z[(long)cc * 1024 + e] : 0.f;
    }
#pragma unroll
    for (int k = 0; k < 8; ++k) s += v[k];
  }
  gsum[ci][ei] = s;
  __syncthreads();

  float off = 0.f;
#pragma unroll
  for (int k = 0; k < 31; ++k)
    if (k < ci) off += gsum[k][ei];

  s = off;
  for (int base = c0; base < c1; base += 8) {
    float v[8];
#pragma unroll
    for (int k = 0; k < 8; ++k) {
      const int cc = base + k;
      v[k] = (cc < c1) ? Z[(long)cc * 1024 + e] : 0.f;
    }
#pragma unroll
    for (int k = 0; k < 8; ++k) {
      const int cc = base + k;
      if (cc < c1) Z[(long)cc * 1024 + e] = s;  // in place: v read first
      s += v[k];
    }
  }
}

// ---------------- term: w = -(L v) ----------------------------------------
// Retained-chunk sweep (640 thr: 20 i x 32 e-slices) + Z1 from LDS.
// LAST=false: v = r (acc), w = t1 ; tvec=t1, acc=r+t1, Z1.
// LAST=true : v = t1 (tvec), w = t2 ; out = 0.5*(acc+t2) + b.
struct TermSh {
  __align__(16) float xl[CC * XPAD];  // 82,240 B
  __align__(16) float Sm[1024];
  float red[640];
  float vvs[CC], wvs[CC];
};

template <bool LAST>
__global__ __launch_bounds__(1024, 4) void k_term(
    const float* __restrict__ At, const float* __restrict__ bvec,
    const float* __restrict__ gram, const float* __restrict__ S,
    float* __restrict__ Z1, float* __restrict__ acc, float* __restrict__ tvec,
    float* __restrict__ out) {
  __shared__ TermSh sh;
  const int c = blockIdx.x, t = threadIdx.x;
  const long i0 = (long)c * CC;

  sh.Sm[t] = S[(long)c * 1024 + t];
  if (t < CC) sh.vvs[t] = LAST ? tvec[i0 + t] : acc[i0 + t];

  const bool sact = (t < 640);
  const int si = t % 20, sb = t / 20;
  float p = 0.f;

  // ---- stage half 0 ----
  float4 ha, hb, hc;
  STAGE_LD(t, ha);
  STAGE_LD(1024 + t, hb);
  if (t < 512) STAGE_LD(2048 + t, hc);
  STAGE_ST(t, ha, sh.xl);
  STAGE_ST(1024 + t, hb, sh.xl);
  if (t < 512) STAGE_ST(2048 + t, hc, sh.xl);
  __syncthreads();

  STAGE_LD(2560 + t, ha);
  STAGE_LD(3584 + t, hb);
  if (t < 512) STAGE_LD(4608 + t, hc);

#define SWEEP_PHASE(H)                                                \
  if (sact) {                                                         \
    _Pragma("unroll") for (int k = 0; k < 4; ++k) {                   \
      const int e0 = (H) * 512 + (sb + 32 * k) * 4;                   \
      const float4 xv = *(const float4*)&sh.xl[si * XPAD + e0];       \
      const float4 sv = *(const float4*)&sh.Sm[e0];                   \
      p = fmaf(xv.x, sv.x, p);                                        \
      p = fmaf(xv.y, sv.y, p);                                        \
      p = fmaf(xv.z, sv.z, p);                                        \
      p = fmaf(xv.w, sv.w, p);                                        \
    }                                                                 \
  }

  SWEEP_PHASE(0)

  STAGE_ST(2560 + t, ha, sh.xl);
  STAGE_ST(3584 + t, hb, sh.xl);
  if (t < 512) STAGE_ST(4608 + t, hc, sh.xl);
  __syncthreads();

  SWEEP_PHASE(1)

  if (sact) sh.red[t] = p;
  __syncthreads();

  if (t < CC) {
    const int i = t;
    float dot = 0.f;
#pragma unroll
    for (int k = 0; k < 32; ++k) dot += sh.red[k * 20 + i];
    const float* grow = gram + (long)c * 190 + i * (i - 1) / 2;
    float g = 0.f;
#pragma unroll 4
    for (int j = 0; j < i; ++j) g = fmaf(grow[j], sh.vvs[j], g);
    const float w = -ETA2 * (dot + g);
    if (LAST) {
      out[i0 + i] = fmaf(0.5f, acc[i0 + i] + w, bvec[i0 + i]);
    } else {
      sh.wvs[i] = w;
      tvec[i0 + i] = w;
      acc[i0 + i] += w;
    }
  }
  if (!LAST) {
    __syncthreads();
    float z = 0.f;
#pragma unroll
    for (int j = 0; j < CC; ++j) z = fmaf(sh.wvs[j], sh.xl[j * XPAD + t], z);
    Z1[(long)c * 1024 + t] = z;
  }
}

extern "C" void kernel_launch(void* const* d_in, const int* in_sizes, int n_in,
                              void* d_out, int out_size, void* d_ws,
                              size_t ws_size, hipStream_t stream) {
  const float* At = (const float*)d_in[0];  // (1024, 20000) row-major
  const float* b  = (const float*)d_in[1];
  const float* w1 = (const float*)d_in[2];
  const float* W2 = (const float*)d_in[3];  // (512, 1023) row-major
  float* out = (float*)d_out;
  float* ws = (float*)d_ws;

  float* gram  = ws + OFF_GRAM;
  float* Zr    = ws + OFF_ZR;   // scanned in place -> S1
  float* Z1    = ws + OFF_Z1;   // scanned in place -> S2
  float* scalp = ws + OFF_SCLP;
  float* acc   = ws + OFF_ACC;
  float* tvec  = ws + OFF_TV;
  float* x0ws  = ws + OFF_X0;

  k_init<<<dim3(53), dim3(1024), 0, stream>>>(At, b, w1, W2, out, scalp, x0ws);
  k_gram<<<dim3(NCH), dim3(1024), 0, stream>>>(At, b, x0ws, gram, Zr, scalp,
                                               acc);
  k_scan<<<dim3(32), dim3(1024), 0, stream>>>(Zr);
  k_term<false><<<dim3(NCH), dim3(1024), 0, stream>>>(At, b, gram, Zr, Z1, acc,
                                                      tvec, out);
  k_scan<<<dim3(32), dim3(1024), 0, stream>>>(Z1);
  k_term<true><<<dim3(NCH), dim3(1024), 0, stream>>>(At, b, gram, Z1, Z1, acc,
                                                     tvec, out);
}

// Round 6
// 228.108 us; speedup vs baseline: 1.1126x; 1.0594x over previous
//
#include <hip/hip_runtime.h>

// FM_FTRL == two unit-lower-triangular solves:
//   alpha_i = -2eta*(x_0.x_i - q0*q_i)  (closed form, K_A=1; alpha_0 = 1)
//   (I+Lh)s = r, Lh[i,j] = 2eta*(x_j.x_i) j<i
//   r_i = 2*(alpha_i^2*T0 - b_i) (i>=1), r_0 = 2*(s0 + T0 - b_0)
//   preds = s/2 + b ;  K_B=2: s ~= r - L r + L^2 r
// R5 postmortem: spill fixed (WRITE 4.9MB, VGPR 64) and bytes cut, but
// 117KB LDS -> 1 block/CU (occ 33%) erased the gain; warm runs are
// L3-resident (hbm_bytes ~5MB) -> limiter is per-CU concurrency, not HBM.
// R6: CC=16 -> ~71KB LDS -> 2 blocks/CU; ZR/Z1 share one ws buffer
// (block c reads S-row c before writing Z-row c); lane mappings made
// e-slice-minor (conflict-free f4 LDS reads); gram partials reduced via
// shfl_xor butterfly (scr block + its LDS traffic deleted).

#define NN 20000
#define CC 16
#define NCH 1250
#define ETA2 2e-5f
#define XPAD 1028  // xl row stride: 16B-aligned rows, 4-bank skew

// ws float offsets (~5.9 MB)
#define OFF_GRAM 0L        // 1250 chunks x 120 packed lower-tri
#define OFF_Z    150016L   // 1250 x 1024; ZR->S1 then Z1->S2, in place
#define OFF_SCLP 1430016L  // [0..31] T0 partials, [32] s0
#define OFF_ACC  1430080L
#define OFF_TV   1450080L
#define OFF_X0   1470080L  // x0 column, contiguous (1024)

// ---------------- k0: T0/s0 partials + x0 stash + b-copy -------------------
__global__ __launch_bounds__(1024) void k_init(
    const float* __restrict__ At, const float* __restrict__ bvec,
    const float* __restrict__ w1, const float* __restrict__ W2,
    float* __restrict__ out, float* __restrict__ scalp,
    float* __restrict__ x0ws) {
  __shared__ float x0s[1024];
  __shared__ float part[16];
  const int bid = blockIdx.x, t = threadIdx.x;
  const int wid = t >> 6, lane = t & 63;

  if (bid < 32) {  // T0 partial over 16 W2 rows
    x0s[t] = (t < 1023) ? At[(long)t * NN] : 0.f;
    __syncthreads();
    const int row = bid * 16 + wid;
    float p = 0.f;
#pragma unroll
    for (int k = 0; k < 16; ++k) {
      const int ci = k * 64 + lane;
      if (ci < 1023) p = fmaf(W2[(long)row * 1023 + ci], x0s[ci], p);
    }
#pragma unroll
    for (int o = 32; o > 0; o >>= 1) p += __shfl_down(p, o);
    if (lane == 0) part[wid] = p * p;
    __syncthreads();
    if (t == 0) {
      float s = 0.f;
#pragma unroll
      for (int k = 0; k < 16; ++k) s += part[k];
      scalp[bid] = s;
    }
  } else if (bid == 32) {  // s0 = w1 . x0 ; stash x0 contiguously
    const float xv = At[(long)t * NN];
    x0ws[t] = xv;
    float p = w1[t] * xv;
#pragma unroll
    for (int o = 32; o > 0; o >>= 1) p += __shfl_down(p, o);
    if (lane == 0) part[wid] = p;
    __syncthreads();
    if (t == 0) {
      float s = 0.f;
#pragma unroll
      for (int k = 0; k < 16; ++k) s += part[k];
      scalp[32] = s;
    }
  } else {  // b-copy: 20 blocks x 1000
    const int i = (bid - 33) * 1000 + t;
    if (t < 1000) out[NN + i] = bvec[i];
  }
}

// Staged-chunk layout: xl[j*XPAD + e] = At[e][i0+j], j<16, e<1024.
// f4 index g in [0,4096): e=g>>2, q=g&3. Stage writes hit banks
// (16q + e) mod 32 across a wave -> 2-way max (free).
#define STAGE_LD(g, dst)                                          \
  {                                                               \
    const int e_ = (g) >> 2, q_ = (g) & 3;                        \
    dst = *(const float4*)(At + (long)e_ * NN + i0 + 4 * q_);     \
  }
#define STAGE_ST(g, src, xl)                                      \
  {                                                               \
    const int e_ = (g) >> 2, q_ = (g) & 3;                        \
    xl[(4 * q_ + 0) * XPAD + e_] = src.x;                         \
    xl[(4 * q_ + 1) * XPAD + e_] = src.y;                         \
    xl[(4 * q_ + 2) * XPAD + e_] = src.z;                         \
    xl[(4 * q_ + 3) * XPAD + e_] = src.w;                         \
  }

// ---------------- k1: packed chunk Grams + alpha + r + Zr ------------------
// gram: 10 lower-tri 4x4 tiles x 32 e-slices = 320 threads (tile=t>>5,
// band=t&31 -> lane-consecutive f4 reads, conflict-free). u: 64 threads.
// Partials reduced with shfl_xor butterfly over the 32-lane band group.
struct GramSh {
  __align__(16) float xl[CC * XPAD];  // 65,792 B
  __align__(16) float x0s[1024];
  float up[64];
  float rs[CC];
  float sc[2];
};
static_assert(sizeof(GramSh) <= 80 * 1024, "LDS too big for 2 blocks/CU");

#define GACC(r, s, RA, RB)                      \
  ac[r][s] = fmaf(RA.x, RB.x, ac[r][s]);        \
  ac[r][s] = fmaf(RA.y, RB.y, ac[r][s]);        \
  ac[r][s] = fmaf(RA.z, RB.z, ac[r][s]);        \
  ac[r][s] = fmaf(RA.w, RB.w, ac[r][s]);

__global__ __launch_bounds__(1024, 4) void k_gram(
    const float* __restrict__ At, const float* __restrict__ bvec,
    const float* __restrict__ x0g, float* __restrict__ gram,
    float* __restrict__ Zr, const float* __restrict__ scalp,
    float* __restrict__ acc) {
  __shared__ GramSh sh;
  const int c = blockIdx.x, t = threadIdx.x;
  const long i0 = (long)c * CC;

  sh.x0s[t] = x0g[t];
  if (t == 0) {
    float T = 0.f;
#pragma unroll
    for (int k = 0; k < 32; ++k) T += scalp[k];
    sh.sc[0] = T;
    sh.sc[1] = scalp[32];
  }

  const bool act = (t < 320);
  const int tile = t >> 5, band = t & 31;
  int a = 0, bb = 0;
  if (act) {
    int r = tile;
    while (r > a) { r -= ++a; }
    bb = r;
  }
  const bool uact = (t >= 320 && t < 384);
  const int uz = t - 320, ub = uz >> 4, ui = uz & 15;
  float4 uac = make_float4(0.f, 0.f, 0.f, 0.f);

  float ac[4][4];
#pragma unroll
  for (int r = 0; r < 4; ++r)
#pragma unroll
    for (int s = 0; s < 4; ++s) ac[r][s] = 0.f;

#define GRAM_PHASE(H)                                                        \
  if (act) {                                                                 \
    _Pragma("unroll") for (int k = 0; k < 4; ++k) {                          \
      const int e0 = (H) * 512 + (band + 32 * k) * 4;                        \
      const float4 A0 = *(const float4*)&sh.xl[(4 * a + 0) * XPAD + e0];     \
      const float4 A1 = *(const float4*)&sh.xl[(4 * a + 1) * XPAD + e0];     \
      const float4 A2 = *(const float4*)&sh.xl[(4 * a + 2) * XPAD + e0];     \
      const float4 A3 = *(const float4*)&sh.xl[(4 * a + 3) * XPAD + e0];     \
      const float4 B0 = *(const float4*)&sh.xl[(4 * bb + 0) * XPAD + e0];    \
      const float4 B1 = *(const float4*)&sh.xl[(4 * bb + 1) * XPAD + e0];    \
      const float4 B2 = *(const float4*)&sh.xl[(4 * bb + 2) * XPAD + e0];    \
      const float4 B3 = *(const float4*)&sh.xl[(4 * bb + 3) * XPAD + e0];    \
      GACC(0, 0, A0, B0) GACC(0, 1, A0, B1) GACC(0, 2, A0, B2)               \
      GACC(0, 3, A0, B3) GACC(1, 0, A1, B0) GACC(1, 1, A1, B1)               \
      GACC(1, 2, A1, B2) GACC(1, 3, A1, B3) GACC(2, 0, A2, B0)               \
      GACC(2, 1, A2, B1) GACC(2, 2, A2, B2) GACC(2, 3, A2, B3)               \
      GACC(3, 0, A3, B0) GACC(3, 1, A3, B1) GACC(3, 2, A3, B2)               \
      GACC(3, 3, A3, B3)                                                     \
    }                                                                        \
  } else if (uact) {                                                         \
    _Pragma("unroll") for (int k = 0; k < 32; ++k) {                         \
      const int e0 = (H) * 512 + ub * 128 + 4 * k;                           \
      const float4 xv = *(const float4*)&sh.xl[ui * XPAD + e0];              \
      const float4 x0 = *(const float4*)&sh.x0s[e0];                         \
      uac.x = fmaf(x0.x, xv.x, uac.x);                                       \
      uac.y = fmaf(x0.y, xv.y, uac.y);                                       \
      uac.z = fmaf(x0.z, xv.z, uac.z);                                       \
      uac.w = fmaf(x0.w, xv.w, uac.w);                                       \
    }                                                                        \
  }

  // stage half 0 (e<512) + barrier
  float4 ha, hb;
  STAGE_LD(t, ha);
  STAGE_LD(1024 + t, hb);
  STAGE_ST(t, ha, sh.xl);
  STAGE_ST(1024 + t, hb, sh.xl);
  __syncthreads();

  // half-1 loads fly over phase-0 compute
  STAGE_LD(2048 + t, ha);
  STAGE_LD(3072 + t, hb);

  GRAM_PHASE(0)

  STAGE_ST(2048 + t, ha, sh.xl);
  STAGE_ST(3072 + t, hb, sh.xl);
  __syncthreads();

  GRAM_PHASE(1)

  // butterfly-reduce gram partials over the 32-lane band group; band-0
  // lanes write packed entries (col<row) straight to global.
  if (act) {
#pragma unroll
    for (int off = 16; off >= 1; off >>= 1)
#pragma unroll
      for (int r = 0; r < 4; ++r)
#pragma unroll
        for (int s = 0; s < 4; ++s) ac[r][s] += __shfl_xor(ac[r][s], off);
    if (band == 0) {
      float* gp = gram + (long)c * 120;
#pragma unroll
      for (int r = 0; r < 4; ++r) {
        const int row = 4 * a + r;
        const int base = row * (row - 1) / 2;
#pragma unroll
        for (int s = 0; s < 4; ++s) {
          const int col = 4 * bb + s;
          if (col < row) gp[base + col] = ac[r][s];
        }
      }
    }
  }
  if (uact) sh.up[uz] = uac.x + uac.y + uac.z + uac.w;
  __syncthreads();

  // alpha (closed form) -> r ; q row = xl[.][1023] (retained)
  if (t < CC) {
    const long gi = i0 + t;
    const float uu = sh.up[t] + sh.up[16 + t] + sh.up[32 + t] + sh.up[48 + t];
    const float qi = sh.xl[t * XPAD + 1023];
    const float q0 = sh.x0s[1023];
    const float al = (gi == 0) ? 1.f : -ETA2 * (uu - q0 * qi);
    const float T0 = sh.sc[0], s0v = sh.sc[1];
    const float bv = bvec[gi];
    float r = 2.f * fmaf(al * al, T0, -bv);
    if (gi == 0) r = 2.f * (s0v + T0 - bv);
    sh.rs[t] = r;
    acc[gi] = r;
  }
  __syncthreads();

  // Zr from retained LDS chunk (lane-consecutive scalar reads)
  {
    float z = 0.f;
#pragma unroll
    for (int j = 0; j < CC; ++j) z = fmaf(sh.rs[j], sh.xl[j * XPAD + t], z);
    Zr[(long)c * 1024 + t] = z;
  }
}

// ---------------- scan: IN PLACE Z -> exclusive prefix S -------------------
// 32 blocks x (32 c-groups x 32 e-lanes); chain 40, loads 8-batched.
__global__ __launch_bounds__(1024) void k_scan(float* __restrict__ Z) {
  __shared__ float gsum[32][33];
  const int t = threadIdx.x;
  const int ei = t & 31, ci = t >> 5;
  const int e = blockIdx.x * 32 + ei;
  const int c0 = ci * 40;
  const int c1 = (c0 + 40 < NCH) ? c0 + 40 : NCH;

  float s = 0.f;
  for (int base = c0; base < c1; base += 8) {
    float v[8];
#pragma unroll
    for (int k = 0; k < 8; ++k) {
      const int cc = base + k;
      v[k] = (cc < c1) ? Z[(long)cc * 1024 + e] : 0.f;
    }
#pragma unroll
    for (int k = 0; k < 8; ++k) s += v[k];
  }
  gsum[ci][ei] = s;
  __syncthreads();

  float off = 0.f;
#pragma unroll
  for (int k = 0; k < 31; ++k)
    if (k < ci) off += gsum[k][ei];

  s = off;
  for (int base = c0; base < c1; base += 8) {
    float v[8];
#pragma unroll
    for (int k = 0; k < 8; ++k) {
      const int cc = base + k;
      v[k] = (cc < c1) ? Z[(long)cc * 1024 + e] : 0.f;
    }
#pragma unroll
    for (int k = 0; k < 8; ++k) {
      const int cc = base + k;
      if (cc < c1) Z[(long)cc * 1024 + e] = s;  // in place: v read first
      s += v[k];
    }
  }
}

// ---------------- term: w = -(L v) ----------------------------------------
// Sweep: 512 threads (16 i x 32 e-slices, si=t>>5, sb=t&31 -> conflict-free
// f4 reads). S and Z1 may ALIAS: row c is read into Sm before Z1-row c is
// written, and block c touches only row c.
// LAST=false: v = r (acc), w = t1 ; tvec=t1, acc=r+t1, Z1.
// LAST=true : v = t1 (tvec), w = t2 ; out = 0.5*(acc+t2) + b.
struct TermSh {
  __align__(16) float xl[CC * XPAD];  // 65,792 B
  __align__(16) float Sm[1024];
  float red[512];
  float vvs[CC], wvs[CC];
};
static_assert(sizeof(TermSh) <= 80 * 1024, "LDS too big for 2 blocks/CU");

template <bool LAST>
__global__ __launch_bounds__(1024, 4) void k_term(
    const float* __restrict__ At, const float* __restrict__ bvec,
    const float* __restrict__ gram, const float* __restrict__ S,
    float* __restrict__ Z1, float* __restrict__ acc, float* __restrict__ tvec,
    float* __restrict__ out) {
  __shared__ TermSh sh;
  const int c = blockIdx.x, t = threadIdx.x;
  const long i0 = (long)c * CC;

  sh.Sm[t] = S[(long)c * 1024 + t];
  if (t < CC) sh.vvs[t] = LAST ? tvec[i0 + t] : acc[i0 + t];

  const bool sact = (t < 512);
  const int si = t >> 5, sb = t & 31;
  float p = 0.f;

#define SWEEP_PHASE(H)                                            \
  if (sact) {                                                     \
    _Pragma("unroll") for (int k = 0; k < 4; ++k) {               \
      const int e0 = (H) * 512 + (sb + 32 * k) * 4;               \
      const float4 xv = *(const float4*)&sh.xl[si * XPAD + e0];   \
      const float4 sv = *(const float4*)&sh.Sm[e0];               \
      p = fmaf(xv.x, sv.x, p);                                    \
      p = fmaf(xv.y, sv.y, p);                                    \
      p = fmaf(xv.z, sv.z, p);                                    \
      p = fmaf(xv.w, sv.w, p);                                    \
    }                                                             \
  }

  float4 ha, hb;
  STAGE_LD(t, ha);
  STAGE_LD(1024 + t, hb);
  STAGE_ST(t, ha, sh.xl);
  STAGE_ST(1024 + t, hb, sh.xl);
  __syncthreads();  // also publishes Sm, vvs

  STAGE_LD(2048 + t, ha);
  STAGE_LD(3072 + t, hb);

  SWEEP_PHASE(0)

  STAGE_ST(2048 + t, ha, sh.xl);
  STAGE_ST(3072 + t, hb, sh.xl);
  __syncthreads();

  SWEEP_PHASE(1)

  if (sact) sh.red[t] = p;
  __syncthreads();

  if (t < CC) {
    const int i = t;
    float dot = 0.f;
#pragma unroll
    for (int k = 0; k < 32; ++k) dot += sh.red[i * 32 + k];
    const float* grow = gram + (long)c * 120 + i * (i - 1) / 2;
    float g = 0.f;
#pragma unroll 4
    for (int j = 0; j < i; ++j) g = fmaf(grow[j], sh.vvs[j], g);
    const float w = -ETA2 * (dot + g);
    if (LAST) {
      out[i0 + i] = fmaf(0.5f, acc[i0 + i] + w, bvec[i0 + i]);
    } else {
      sh.wvs[i] = w;
      tvec[i0 + i] = w;
      acc[i0 + i] += w;
    }
  }
  if (!LAST) {
    __syncthreads();
    float z = 0.f;
#pragma unroll
    for (int j = 0; j < CC; ++j) z = fmaf(sh.wvs[j], sh.xl[j * XPAD + t], z);
    Z1[(long)c * 1024 + t] = z;
  }
}

extern "C" void kernel_launch(void* const* d_in, const int* in_sizes, int n_in,
                              void* d_out, int out_size, void* d_ws,
                              size_t ws_size, hipStream_t stream) {
  const float* At = (const float*)d_in[0];  // (1024, 20000) row-major
  const float* b  = (const float*)d_in[1];
  const float* w1 = (const float*)d_in[2];
  const float* W2 = (const float*)d_in[3];  // (512, 1023) row-major
  float* out = (float*)d_out;
  float* ws = (float*)d_ws;

  float* gram  = ws + OFF_GRAM;
  float* Zsh   = ws + OFF_Z;    // ZR -> S1 -> (overwritten) Z1 -> S2
  float* scalp = ws + OFF_SCLP;
  float* acc   = ws + OFF_ACC;
  float* tvec  = ws + OFF_TV;
  float* x0ws  = ws + OFF_X0;

  k_init<<<dim3(53), dim3(1024), 0, stream>>>(At, b, w1, W2, out, scalp, x0ws);
  k_gram<<<dim3(NCH), dim3(1024), 0, stream>>>(At, b, x0ws, gram, Zsh, scalp,
                                               acc);
  k_scan<<<dim3(32), dim3(1024), 0, stream>>>(Zsh);
  k_term<false><<<dim3(NCH), dim3(1024), 0, stream>>>(At, b, gram, Zsh, Zsh,
                                                      acc, tvec, out);
  k_scan<<<dim3(32), dim3(1024), 0, stream>>>(Zsh);
  k_term<true><<<dim3(NCH), dim3(1024), 0, stream>>>(At, b, gram, Zsh, Zsh,
                                                     acc, tvec, out);
}